// Round 3
// baseline (434.107 us; speedup 1.0000x reference)
//
#include <hip/hip_runtime.h>
#include <math.h>

// N=5, B=8, C=256, H*W=1024
#define NN 5
#define CC 256
#define SSP 1024
#define BB 8
#define THRESHV 0.3f

typedef __attribute__((ext_vector_type(8))) short short8;   // 8 bf16 = one MFMA A/B frag
typedef __attribute__((ext_vector_type(4))) float f32x4;    // MFMA 16x16 accumulator

// ---------------- ws layout (bytes) ----------------
// X split planes, k-minor: [(j*8+b)*3+sp][s:1024][k:256] bf16
#define XW_OFF   0ull
#define XW_PLANE ((size_t)SSP * CC * 2)                 // 524288
#define XW_SIZE  ((size_t)NN * BB * 3 * XW_PLANE)       // 62,914,560
// A = W1+W2 split planes, k-minor: [i*3+sp][o:256][k:256]
#define AW_OFF   XW_SIZE
#define AW_PLANE ((size_t)CC * CC * 2)                  // 131072
#define AW_SIZE  ((size_t)NN * 3 * AW_PLANE)            // 1,966,080
#define W2_OFF   (AW_OFF + AW_SIZE)
#define WS_NEED  (W2_OFF + AW_SIZE)                     // ~63.8 MiB

// ---- exact 3-way bf16 split (Dekker-style; residuals exact in fp32) ----
static __device__ __forceinline__ unsigned short f2bf(float f) {
    unsigned int u = __builtin_bit_cast(unsigned int, f);
    u = u + 0x7fffu + ((u >> 16) & 1u);          // RNE to bf16
    return (unsigned short)(u >> 16);
}
static __device__ __forceinline__ float bf2f(unsigned short h) {
    unsigned int u = ((unsigned int)h) << 16;
    return __builtin_bit_cast(float, u);
}
static __device__ __forceinline__ void split3(float a, unsigned short& h,
                                              unsigned short& m, unsigned short& l) {
    h = f2bf(a); float r1 = a - bf2f(h);
    m = f2bf(r1); float r2 = r1 - bf2f(m);
    l = f2bf(r2);
}
static __device__ __forceinline__ f32x4 MF(short8 a, short8 b, f32x4 c) {
    return __builtin_amdgcn_mfma_f32_16x16x32_bf16(a, b, c, 0, 0, 0);
}

// async global->LDS, 16B per lane; LDS dest = uniform base + lane*16
#define GLD16(gp, lp) __builtin_amdgcn_global_load_lds(                          \
        (const __attribute__((address_space(1))) unsigned int*)(gp),             \
        (__attribute__((address_space(3))) unsigned int*)(lp), 16, 0, 0)

// counted vmcnt wait (never 0 in the main loop) + scheduler pin (rule #18)
#define WAITV(N) do { asm volatile("s_waitcnt vmcnt(" #N ")" ::: "memory");     \
                      __builtin_amdgcn_sched_barrier(0); } while (0)

// ================= pre-pass: split weights =================
__global__ __launch_bounds__(256)
void prep_w(const float* __restrict__ w, unsigned char* __restrict__ ws) {
    const int id = blockIdx.x * 256 + threadIdx.x;   // 40960 = 5*256*32
    const int i  = id >> 13;
    const int o  = (id >> 5) & 255;
    const int ko = id & 31;                          // k-oct
    const float* gw = w + (size_t)(i * CC + o) * (2 * CC) + ko * 8;
    float av[8], wv[8];
    #pragma unroll
    for (int kk = 0; kk < 8; kk++) {
        wv[kk] = gw[CC + kk];
        av[kk] = gw[kk] + wv[kk];
    }
    unsigned short h[8], m[8], l[8];
    short8 H, M, L;
    #pragma unroll
    for (int kk = 0; kk < 8; kk++) split3(av[kk], h[kk], m[kk], l[kk]);
    #pragma unroll
    for (int kk = 0; kk < 8; kk++) { H[kk] = (short)h[kk]; M[kk] = (short)m[kk]; L[kk] = (short)l[kk]; }
    {
        unsigned char* p = ws + AW_OFF + (size_t)((i * 3) * CC + o) * 512 + ko * 16;
        *(short8*)(p)                = H;
        *(short8*)(p + CC * 512)     = M;
        *(short8*)(p + 2 * CC * 512) = L;
    }
    #pragma unroll
    for (int kk = 0; kk < 8; kk++) split3(wv[kk], h[kk], m[kk], l[kk]);
    #pragma unroll
    for (int kk = 0; kk < 8; kk++) { H[kk] = (short)h[kk]; M[kk] = (short)m[kk]; L[kk] = (short)l[kk]; }
    {
        unsigned char* p = ws + W2_OFF + (size_t)((i * 3) * CC + o) * 512 + ko * 16;
        *(short8*)(p)                = H;
        *(short8*)(p + CC * 512)     = M;
        *(short8*)(p + 2 * CC * 512) = L;
    }
}

// ================= pre-pass: split + transpose x (1280 blocks) ======
__global__ __launch_bounds__(256)
void prep_x(const float* __restrict__ x, unsigned char* __restrict__ ws) {
    const int blk = blockIdx.x;          // 1280 = 40 jb * 8 kc * 4 r
    const int r   = blk & 3;
    const int kc  = (blk >> 2) & 7;
    const int jb  = blk >> 5;            // j*8+b
    const int k0  = kc * 32;
    const int s   = threadIdx.x + 256 * r;
    const float* gx = x + ((size_t)jb * CC + k0) * SSP + s;
    unsigned char* w0 = ws + XW_OFF + (size_t)(jb * 3) * XW_PLANE
                      + (size_t)s * 512 + (size_t)k0 * 2;
    #pragma unroll
    for (int oct = 0; oct < 4; oct++) {
        float v[8];
        #pragma unroll
        for (int kk = 0; kk < 8; kk++) v[kk] = gx[(size_t)(oct * 8 + kk) * SSP];
        unsigned short h[8], m[8], l[8];
        #pragma unroll
        for (int kk = 0; kk < 8; kk++) split3(v[kk], h[kk], m[kk], l[kk]);
        short8 H, M, L;
        #pragma unroll
        for (int kk = 0; kk < 8; kk++) { H[kk] = (short)h[kk]; M[kk] = (short)m[kk]; L[kk] = (short)l[kk]; }
        *(short8*)(w0 + oct * 16)                 = H;
        *(short8*)(w0 + XW_PLANE + oct * 16)      = M;
        *(short8*)(w0 + 2 * XW_PLANE + oct * 16)  = L;
    }
}

// ================= main pipelined kernel (T3/T4: dbuf + counted vmcnt) =======
// 512 threads = 8 waves. Quadrant q = w&3 (16x16 of the 32x32 o/s tile);
// iset = w>>2 splits i: iset0 -> i={0,1}, iset1 -> i={2,3,4} (fallback-proven).
// LDS 2 x 61440 B buffers; each = 15 X planes (2KB) + 15 W2 planes (2KB).
// Per chunk k: [af(k) global->reg] [GLD16 stage(k+1) -> other buf]
//   [s_waitcnt vmcnt(8/7) = in-flight stage(k+1) count; chunk-k loads retired
//    in-order] [s_barrier] [compute(k), setprio around MFMA cluster]
//   [lgkmcnt(0); s_barrier]  <- frees buf for the stage two chunks ahead.
// No vmcnt(0) in the main loop: the ~55%-of-cycles drain stall is removed.
// Numerics: identical product set + accumulation order as R2 (bit-exact).
#define PLOADAF(IB_, NI_)                                                       \
    {                                                                           \
        _Pragma("unroll")                                                       \
        for (int ii = 0; ii < NI_; ii++)                                        \
            _Pragma("unroll")                                                   \
            for (int sp = 0; sp < 3; sp++)                                      \
                af[ii][sp] = *(const short8*)(ws + vAW                          \
                    + (unsigned)(((IB_ + ii) * 3 + sp) * AW_PLANE)              \
                    + (unsigned)(k * 64));                                      \
    }

#define PCHUNK(IB_, NI_)                                                        \
    {                                                                           \
        _Pragma("unroll")                                                       \
        for (int j = 0; j < NN; j++) {                                          \
            const unsigned char* xp = SB + cb + (unsigned)(j * 3) * 2048u + xb; \
            const short8 x0 = *(const short8*)(xp);                             \
            const short8 x1 = *(const short8*)(xp + 2048);                      \
            const short8 x2 = *(const short8*)(xp + 4096);                      \
            _Pragma("unroll")                                                   \
            for (int ii = 0; ii < NI_; ii++) {                                  \
                f32x4 c = accY[ii][j];                                          \
                c = MF(af[ii][0], x0, c);                                       \
                c = MF(af[ii][0], x1, c);                                       \
                c = MF(af[ii][1], x0, c);                                       \
                c = MF(af[ii][1], x1, c);                                       \
                c = MF(af[ii][0], x2, c);                                       \
                c = MF(af[ii][2], x0, c);                                       \
                accY[ii][j] = c;                                                \
            }                                                                   \
            if (j >= IB_ && j < IB_ + NI_) {                                    \
                const unsigned char* wp = SB + cb + 30720u                      \
                    + (unsigned)(j * 3) * 2048u + wb;                           \
                const short8 w0f = *(const short8*)(wp);                        \
                const short8 w1f = *(const short8*)(wp + 2048);                 \
                const short8 w2f = *(const short8*)(wp + 4096);                 \
                f32x4 u = accU[j - IB_];                                        \
                u = MF(w0f, x0, u);                                             \
                u = MF(w0f, x1, u);                                             \
                u = MF(w1f, x0, u);                                             \
                u = MF(w1f, x1, u);                                             \
                u = MF(w0f, x2, u);                                             \
                u = MF(w2f, x0, u);                                             \
                accU[j - IB_] = u;                                              \
            }                                                                   \
        }                                                                       \
    }

#define PEPI(IB_, NI_)                                                          \
    {                                                                           \
        _Pragma("unroll")                                                       \
        for (int ii = 0; ii < NI_; ii++) {                                      \
            const int i = IB_ + ii;                                             \
            _Pragma("unroll")                                                   \
            for (int r = 0; r < 4; r++) {                                       \
                const float uu = accU[ii][r] + bias[i * CC + og0 + r];          \
                float e[NN]; float mx = 0.f;                                    \
                _Pragma("unroll")                                               \
                for (int j = 0; j < NN; j++) {                                  \
                    float d = fabsf(xe[j][r] - (accY[ii][j][r] + uu));          \
                    d = (d > THRESHV) ? d : 0.f;                                \
                    e[j] = d; mx = fmaxf(mx, d);                                \
                }                                                               \
                float sum = 0.f, hv = 0.f;                                      \
                _Pragma("unroll")                                               \
                for (int j = 0; j < NN; j++) {                                  \
                    const float p = __expf(e[j] - mx);                          \
                    sum += p; hv += p * xe[j][r];                               \
                }                                                               \
                out[(size_t)((i * BB + b) * CC + og0 + r) * SSP + sg] = hv / sum; \
            }                                                                   \
        }                                                                       \
    }

__global__ __launch_bounds__(512, 2)
void fub_pipe(const float* __restrict__ x, const float* __restrict__ bias,
              const unsigned char* __restrict__ ws, float* __restrict__ out)
{
    __shared__ unsigned char SB[122880];

    const int tid  = threadIdx.x;
    const int b    = blockIdx.z;
    const int o0   = blockIdx.y * 32;
    const int s0   = blockIdx.x * 32;
    const int lane = tid & 63;
    const int w    = tid >> 6;            // 0..7
    const int q    = w & 3;               // output quadrant
    const int iset = w >> 2;              // 0: i={0,1}  1: i={2,3,4}
    const int oh   = q >> 1, sh = q & 1;
    const int qd   = lane >> 4;
    const int m_   = lane & 15;
    const int ar   = 16 * oh + m_;        // o row for A/W2 frags
    const int xr   = 16 * sh + m_;        // s row for X frags

    // ---- DMA staging: 60 slots over 8 waves (waves 0-3: 8, waves 4-7: 7) ----
    // slots 0..29 : X planes (p = slot>>1 = j*3+sp), rows are s-rows
    // slots 30..59: W2 planes (p = (slot-30)>>1 = i*3+sp), rows are o-rows
    const int sbase = (w < 4) ? w * 8 : 32 + (w - 4) * 7;
    const int nsl   = (w < 4) ? 8 : 7;
    unsigned gOff[8];
    #pragma unroll
    for (int t = 0; t < 8; t++) {
        if (t < nsl) {
            const int slot = sbase + t;
            if (slot < 30) {
                const int p  = slot >> 1;
                const int jj = p / 3, sp = p - 3 * jj;
                const int u  = (slot & 1) * 64 + lane;
                const int sr = u >> 2;
                const int oc = (u & 3) ^ (sr & 3) ^ ((sr >> 2) & 3);
                gOff[t] = (unsigned)(((jj * BB + b) * 3 + sp) * XW_PLANE)
                        + (unsigned)((s0 + sr) * 512 + oc * 16);
            } else {
                const int sl = slot - 30;
                const int p  = sl >> 1;
                const int u  = (sl & 1) * 64 + lane;
                const int sr = u >> 2;
                const int oc = (u & 3) ^ (sr & 3) ^ ((sr >> 2) & 3);
                gOff[t] = (unsigned)W2_OFF
                        + (unsigned)((p * CC + o0 + sr) * 512 + oc * 16);
            }
        } else {
            gOff[t] = 0;
        }
    }

    // ---- A frag per-lane base (k-minor planes) ----
    const unsigned vAW = (unsigned)AW_OFF + (unsigned)(o0 + ar) * 512u + (unsigned)qd * 16u;
    // X / W2 frag LDS byte offsets (within plane, swizzled)
    const unsigned xb = (unsigned)(xr * 4 + (qd ^ (xr & 3) ^ ((xr >> 2) & 3))) * 16u;
    const unsigned wb = (unsigned)(ar * 4 + (qd ^ (ar & 3) ^ ((ar >> 2) & 3))) * 16u;

    f32x4 accY[3][NN];
    f32x4 accU[3];
    #pragma unroll
    for (int ii = 0; ii < 3; ii++) {
        accU[ii] = (f32x4){0.f, 0.f, 0.f, 0.f};
        #pragma unroll
        for (int j = 0; j < NN; j++) accY[ii][j] = (f32x4){0.f, 0.f, 0.f, 0.f};
    }

    // ---- prologue: stage chunk 0 -> buffer 0 ----
    #pragma unroll
    for (int t = 0; t < 8; t++) {
        if (t < nsl) GLD16(ws + gOff[t], SB + (sbase + t) * 1024);
    }

    #pragma unroll 1
    for (int k = 0; k < 8; k++) {
        const unsigned cb = (unsigned)(k & 1) * 61440u;   // compute buffer
        const unsigned nb = 61440u - cb;                  // stage buffer

        // A frags for this chunk (issued before stage(k+1): retired by the wait)
        short8 af[3][3];
        if (iset == 0) PLOADAF(0, 2) else PLOADAF(2, 3)

        if (k < 7) {
            // stage chunk k+1 into the other buffer
            #pragma unroll
            for (int t = 0; t < 8; t++) {
                if (t < nsl) {
                    gOff[t] += 64;
                    GLD16(ws + gOff[t], SB + nb + (sbase + t) * 1024);
                }
            }
            // wait: own chunk-k stage + af(k) retired; stage(k+1) stays in flight
            if (w < 4) WAITV(8); else WAITV(7);
        } else {
            WAITV(0);
        }
        __builtin_amdgcn_s_barrier();          // all waves' chunk-k data in LDS
        __builtin_amdgcn_sched_barrier(0);

        __builtin_amdgcn_s_setprio(1);
        if (iset == 0) PCHUNK(0, 2) else PCHUNK(2, 3)
        __builtin_amdgcn_s_setprio(0);

        asm volatile("s_waitcnt lgkmcnt(0)" ::: "memory");
        __builtin_amdgcn_sched_barrier(0);
        __builtin_amdgcn_s_barrier();          // frees cb for stage at k+1
        __builtin_amdgcn_sched_barrier(0);
    }

    // ---------------- epilogue (C/D: col=lane&15, row=qd*4+reg) ----------------
    const int sg  = s0 + 16 * sh + m_;
    const int og0 = o0 + 16 * oh + 4 * qd;

    float xe[NN][4];
    #pragma unroll
    for (int j = 0; j < NN; j++) {
        const float* px = x + (size_t)((j * BB + b) * CC + og0) * SSP + sg;
        #pragma unroll
        for (int r = 0; r < 4; r++) xe[j][r] = px[r * SSP];
    }

    if (iset == 0) PEPI(0, 2) else PEPI(2, 3)
}

// ================= fallback (R2 kernel, self-splitting; known-good) ==========
static __device__ __forceinline__ void st4(unsigned short* p, unsigned short a,
                                           unsigned short b, unsigned short c, unsigned short d) {
    ushort4 v; v.x = a; v.y = b; v.z = c; v.w = d;
    *(ushort4*)p = v;
}
#define XB 15360
__global__ __launch_bounds__(512, 2)
void fub_mfma(const float* __restrict__ x, const float* __restrict__ w,
              const float* __restrict__ bias, float* __restrict__ out)
{
    __shared__ unsigned short S[30720];
    const int tid = threadIdx.x;
    const int b = blockIdx.z, o0 = blockIdx.y * 32, s0 = blockIdx.x * 32;
    const int lane = tid & 63, wv = tid >> 6;
    const int q = wv & 3, oh = q >> 1, sh = q & 1, iset = wv >> 2, qd = lane >> 4;
    const int sub = tid >> 8, t = tid & 255;
    const int wo = t >> 3, wkg = t & 7, xs = t & 31, xkq = t >> 5;
    const int wbase = wo * 32 + (((wkg >> 1) ^ ((wo >> 1) & 3)) << 3) + ((wkg & 1) << 2);
    const int xbase = xs * 32 + (((xkq >> 1) ^ ((xs >> 1) & 3)) << 3) + ((xkq & 1) << 2);
    const int ar = 16 * oh + (lane & 15), xr = 16 * sh + (lane & 15);
    const int asw8 = ((qd ^ ((ar >> 1) & 3)) << 3), xsw8 = ((qd ^ ((xr >> 1) & 3)) << 3);
    const int arow32 = ar * 32, xrow32 = xr * 32;
    f32x4 accY[3][5]; f32x4 accU[3];
    #pragma unroll
    for (int ii = 0; ii < 3; ii++) {
        accU[ii] = (f32x4){0.f, 0.f, 0.f, 0.f};
        #pragma unroll
        for (int j = 0; j < NN; j++) accY[ii][j] = (f32x4){0.f, 0.f, 0.f, 0.f};
    }
    float w2sav[3][4];
    #pragma unroll 1
    for (int k0 = 0; k0 < CC; k0 += 32) {
        if (k0) __syncthreads();
        #pragma unroll
        for (int rep = 0; rep < 3; rep++) {
            const int i = rep * 2 + sub;
            if (i < NN) {
                const float* gw = w + (size_t)(i * CC + o0 + wo) * (2 * CC) + k0 + wkg * 4;
                const float4 w1 = *(const float4*)gw;
                const float4 w2 = *(const float4*)(gw + CC);
                w2sav[rep][0] = w2.x; w2sav[rep][1] = w2.y; w2sav[rep][2] = w2.z; w2sav[rep][3] = w2.w;
                float av[4] = {w1.x + w2.x, w1.y + w2.y, w1.z + w2.z, w1.w + w2.w};
                unsigned short h[4], m[4], l[4];
                #pragma unroll
                for (int r = 0; r < 4; r++) split3(av[r], h[r], m[r], l[r]);
                unsigned short* p = &S[i * 3 * 1024 + wbase];
                st4(p, h[0], h[1], h[2], h[3]); st4(p + 1024, m[0], m[1], m[2], m[3]); st4(p + 2048, l[0], l[1], l[2], l[3]);
            }
        }
        #pragma unroll
        for (int rep = 0; rep < 3; rep++) {
            const int j = rep * 2 + sub;
            if (j < NN) {
                const float* gx = x + (size_t)((j * BB + b) * CC + k0 + xkq * 4) * SSP + s0 + xs;
                float v[4] = {gx[0], gx[SSP], gx[2 * SSP], gx[3 * SSP]};
                unsigned short h[4], m[4], l[4];
                #pragma unroll
                for (int r = 0; r < 4; r++) split3(v[r], h[r], m[r], l[r]);
                unsigned short* p = &S[XB + j * 3 * 1024 + xbase];
                st4(p, h[0], h[1], h[2], h[3]); st4(p + 1024, m[0], m[1], m[2], m[3]); st4(p + 2048, l[0], l[1], l[2], l[3]);
            }
        }
        __syncthreads();
        short8 xf[NN][3];
        #pragma unroll
        for (int j = 0; j < NN; j++)
            #pragma unroll
            for (int sp = 0; sp < 3; sp++)
                xf[j][sp] = *(const short8*)&S[XB + (j * 3 + sp) * 1024 + xrow32 + xsw8];
#define YPL(IB_, NI_)                                                           \
        {                                                                       \
            _Pragma("unroll")                                                   \
            for (int ii = 0; ii < NI_; ii++) {                                  \
                const int i = IB_ + ii;                                         \
                const unsigned short* ap = &S[i * 3 * 1024 + arow32 + asw8];    \
                const short8 ah = *(const short8*)(ap);                         \
                const short8 am = *(const short8*)(ap + 1024);                  \
                const short8 al = *(const short8*)(ap + 2048);                  \
                _Pragma("unroll")                                               \
                for (int j = 0; j < NN; j++) {                                  \
                    f32x4 c = accY[ii][j];                                      \
                    c = MF(ah, xf[j][0], c); c = MF(ah, xf[j][1], c);           \
                    c = MF(am, xf[j][0], c); c = MF(am, xf[j][1], c);           \
                    c = MF(ah, xf[j][2], c); c = MF(al, xf[j][0], c);           \
                    accY[ii][j] = c;                                            \
                }                                                               \
            }                                                                   \
        }
        if (iset == 0) { YPL(0, 2) } else { YPL(2, 3) }
        __syncthreads();
        #pragma unroll
        for (int rep = 0; rep < 3; rep++) {
            const int i = rep * 2 + sub;
            if (i < NN) {
                unsigned short h[4], m[4], l[4];
                #pragma unroll
                for (int r = 0; r < 4; r++) split3(w2sav[rep][r], h[r], m[r], l[r]);
                unsigned short* p = &S[i * 3 * 1024 + wbase];
                st4(p, h[0], h[1], h[2], h[3]); st4(p + 1024, m[0], m[1], m[2], m[3]); st4(p + 2048, l[0], l[1], l[2], l[3]);
            }
        }
        __syncthreads();
#define UPL(IB_, NI_)                                                           \
        {                                                                       \
            _Pragma("unroll")                                                   \
            for (int ii = 0; ii < NI_; ii++) {                                  \
                const int i = IB_ + ii;                                         \
                const unsigned short* wp = &S[i * 3 * 1024 + arow32 + asw8];    \
                const short8 wh = *(const short8*)(wp);                         \
                const short8 wm = *(const short8*)(wp + 1024);                  \
                const short8 wl = *(const short8*)(wp + 2048);                  \
                f32x4 u = accU[ii];                                             \
                u = MF(wh, xf[i][0], u); u = MF(wh, xf[i][1], u);               \
                u = MF(wm, xf[i][0], u); u = MF(wm, xf[i][1], u);               \
                u = MF(wh, xf[i][2], u); u = MF(wl, xf[i][0], u);               \
                accU[ii] = u;                                                   \
            }                                                                   \
        }
        if (iset == 0) { UPL(0, 2) } else { UPL(2, 3) }
    }
    const int sg = s0 + 16 * sh + (lane & 15);
    const int og0 = o0 + 16 * oh + 4 * qd;
    float xe[NN][4];
    #pragma unroll
    for (int j = 0; j < NN; j++) {
        const float* px = x + (size_t)((j * BB + b) * CC + og0) * SSP + sg;
        #pragma unroll
        for (int r = 0; r < 4; r++) xe[j][r] = px[r * SSP];
    }
#define EPI(IB_, NI_)                                                           \
    {                                                                           \
        _Pragma("unroll")                                                       \
        for (int ii = 0; ii < NI_; ii++) {                                      \
            const int i = IB_ + ii;                                             \
            _Pragma("unroll")                                                   \
            for (int r = 0; r < 4; r++) {                                       \
                const float uu = accU[ii][r] + bias[i * CC + og0 + r];          \
                float e[NN]; float mx = 0.f;                                    \
                _Pragma("unroll")                                               \
                for (int j = 0; j < NN; j++) {                                  \
                    float d = fabsf(xe[j][r] - (accY[ii][j][r] + uu));          \
                    d = (d > THRESHV) ? d : 0.f;                                \
                    e[j] = d; mx = fmaxf(mx, d);                                \
                }                                                               \
                float sum = 0.f, hv = 0.f;                                      \
                _Pragma("unroll")                                               \
                for (int j = 0; j < NN; j++) {                                  \
                    const float p = __expf(e[j] - mx);                          \
                    sum += p; hv += p * xe[j][r];                               \
                }                                                               \
                out[(size_t)((i * BB + b) * CC + og0 + r) * SSP + sg] = hv / sum; \
            }                                                                   \
        }                                                                       \
    }
    if (iset == 0) { EPI(0, 2) } else { EPI(2, 3) }
}

extern "C" void kernel_launch(void* const* d_in, const int* in_sizes, int n_in,
                              void* d_out, int out_size, void* d_ws, size_t ws_size,
                              hipStream_t stream) {
    const float* x      = (const float*)d_in[0];
    const float* conv_w = (const float*)d_in[1];
    const float* conv_b = (const float*)d_in[2];
    float* out = (float*)d_out;

    if (ws_size >= WS_NEED) {
        unsigned char* ws = (unsigned char*)d_ws;
        prep_w<<<160, 256, 0, stream>>>(conv_w, ws);
        prep_x<<<1280, 256, 0, stream>>>(x, ws);
        dim3 grid(SSP / 32, CC / 32, BB);   // 2048 blocks, 8 waves each
        fub_pipe<<<grid, 512, 0, stream>>>(x, conv_b, ws, out);
    } else {
        fub_mfma<<<dim3(SSP / 32, CC / 32, BB), 512, 0, stream>>>(x, conv_w, conv_b, out);
    }
}

// Round 4
// 371.056 us; speedup vs baseline: 1.1699x; 1.1699x over previous
//
#include <hip/hip_runtime.h>
#include <math.h>

// N=5, B=8, C=256, H*W=1024
#define NN 5
#define CC 256
#define SSP 1024
#define BB 8
#define THRESHV 0.3f

typedef __attribute__((ext_vector_type(8))) short short8;   // 8 bf16 = one MFMA A/B frag
typedef __attribute__((ext_vector_type(4))) float f32x4;    // MFMA 16x16 accumulator

// ---------------- ws layout (bytes) ----------------
// X split planes, k-minor: [(j*8+b)*3+sp][s:1024][k:256] bf16
#define XW_OFF   0ull
#define XW_PLANE ((size_t)SSP * CC * 2)                 // 524288
#define XW_SIZE  ((size_t)NN * BB * 3 * XW_PLANE)       // 62,914,560
// A = W1+W2 split planes, k-minor: [i*3+sp][o:256][k:256]
#define AW_OFF   XW_SIZE
#define AW_PLANE ((size_t)CC * CC * 2)                  // 131072
#define AW_SIZE  ((size_t)NN * 3 * AW_PLANE)            // 1,966,080
#define W2_OFF   (AW_OFF + AW_SIZE)
#define WS_NEED  (W2_OFF + AW_SIZE)                     // ~63.8 MiB

// ---- exact 3-way bf16 split (Dekker-style; residuals exact in fp32) ----
static __device__ __forceinline__ unsigned short f2bf(float f) {
    unsigned int u = __builtin_bit_cast(unsigned int, f);
    u = u + 0x7fffu + ((u >> 16) & 1u);          // RNE to bf16
    return (unsigned short)(u >> 16);
}
static __device__ __forceinline__ float bf2f(unsigned short h) {
    unsigned int u = ((unsigned int)h) << 16;
    return __builtin_bit_cast(float, u);
}
static __device__ __forceinline__ void split3(float a, unsigned short& h,
                                              unsigned short& m, unsigned short& l) {
    h = f2bf(a); float r1 = a - bf2f(h);
    m = f2bf(r1); float r2 = r1 - bf2f(m);
    l = f2bf(r2);
}
static __device__ __forceinline__ f32x4 MF(short8 a, short8 b, f32x4 c) {
    return __builtin_amdgcn_mfma_f32_16x16x32_bf16(a, b, c, 0, 0, 0);
}

// async global->LDS, 16B per lane; LDS dest = uniform base + lane*16
#define GLD16(gp, lp) __builtin_amdgcn_global_load_lds(                          \
        (const __attribute__((address_space(1))) unsigned int*)(gp),             \
        (__attribute__((address_space(3))) unsigned int*)(lp), 16, 0, 0)

// counted vmcnt wait (never 0 in the main loop) + scheduler pin (rule #18)
#define WAITV(N) do { asm volatile("s_waitcnt vmcnt(" #N ")" ::: "memory");     \
                      __builtin_amdgcn_sched_barrier(0); } while (0)

// ================= pre-pass: split weights =================
__global__ __launch_bounds__(256)
void prep_w(const float* __restrict__ w, unsigned char* __restrict__ ws) {
    const int id = blockIdx.x * 256 + threadIdx.x;   // 40960 = 5*256*32
    const int i  = id >> 13;
    const int o  = (id >> 5) & 255;
    const int ko = id & 31;                          // k-oct
    const float* gw = w + (size_t)(i * CC + o) * (2 * CC) + ko * 8;
    float av[8], wv[8];
    #pragma unroll
    for (int kk = 0; kk < 8; kk++) {
        wv[kk] = gw[CC + kk];
        av[kk] = gw[kk] + wv[kk];
    }
    unsigned short h[8], m[8], l[8];
    short8 H, M, L;
    #pragma unroll
    for (int kk = 0; kk < 8; kk++) split3(av[kk], h[kk], m[kk], l[kk]);
    #pragma unroll
    for (int kk = 0; kk < 8; kk++) { H[kk] = (short)h[kk]; M[kk] = (short)m[kk]; L[kk] = (short)l[kk]; }
    {
        unsigned char* p = ws + AW_OFF + (size_t)((i * 3) * CC + o) * 512 + ko * 16;
        *(short8*)(p)                = H;
        *(short8*)(p + CC * 512)     = M;
        *(short8*)(p + 2 * CC * 512) = L;
    }
    #pragma unroll
    for (int kk = 0; kk < 8; kk++) split3(wv[kk], h[kk], m[kk], l[kk]);
    #pragma unroll
    for (int kk = 0; kk < 8; kk++) { H[kk] = (short)h[kk]; M[kk] = (short)m[kk]; L[kk] = (short)l[kk]; }
    {
        unsigned char* p = ws + W2_OFF + (size_t)((i * 3) * CC + o) * 512 + ko * 16;
        *(short8*)(p)                = H;
        *(short8*)(p + CC * 512)     = M;
        *(short8*)(p + 2 * CC * 512) = L;
    }
}

// ================= pre-pass: split + transpose x (1280 blocks) ======
__global__ __launch_bounds__(256)
void prep_x(const float* __restrict__ x, unsigned char* __restrict__ ws) {
    const int blk = blockIdx.x;          // 1280 = 40 jb * 8 kc * 4 r
    const int r   = blk & 3;
    const int kc  = (blk >> 2) & 7;
    const int jb  = blk >> 5;            // j*8+b
    const int k0  = kc * 32;
    const int s   = threadIdx.x + 256 * r;
    const float* gx = x + ((size_t)jb * CC + k0) * SSP + s;
    unsigned char* w0 = ws + XW_OFF + (size_t)(jb * 3) * XW_PLANE
                      + (size_t)s * 512 + (size_t)k0 * 2;
    #pragma unroll
    for (int oct = 0; oct < 4; oct++) {
        float v[8];
        #pragma unroll
        for (int kk = 0; kk < 8; kk++) v[kk] = gx[(size_t)(oct * 8 + kk) * SSP];
        unsigned short h[8], m[8], l[8];
        #pragma unroll
        for (int kk = 0; kk < 8; kk++) split3(v[kk], h[kk], m[kk], l[kk]);
        short8 H, M, L;
        #pragma unroll
        for (int kk = 0; kk < 8; kk++) { H[kk] = (short)h[kk]; M[kk] = (short)m[kk]; L[kk] = (short)l[kk]; }
        *(short8*)(w0 + oct * 16)                 = H;
        *(short8*)(w0 + XW_PLANE + oct * 16)      = M;
        *(short8*)(w0 + 2 * XW_PLANE + oct * 16)  = L;
    }
}

// ================= main: R2 structure + X double-buffer (T3/T4) =============
// 256 thr / 4 waves / NI=5 per wave (180 MFMA/wave/chunk, balanced) —
// preserves R2's 2 blocks/CU cross-block overlap.
// LDS 81920 B/block (2 blocks = exactly 160 KB/CU):
//   [0,30720)      xbuf0   (15 X planes x 2KB)
//   [30720,61440)  xbuf1
//   [61440,81920)  W2 h/m  (10 planes (i*2+sp), single-buffered)
// Per chunk k:
//   1. af(k) 15 + wfl(k) 5 reg loads (W2-lo lives in regs: LDS budget)
//   2. stage X(k+1) -> other xbuf (GLD16, 8/7 slots per wave)
//   3. WAITV(8/7): drains X(k), W2hm(k), af, wfl; X(k+1) STAYS IN FLIGHT
//   4. s_barrier -> 5. compute (setprio around MFMA)
//   6. lgkmcnt(0) + s_barrier (frees xbuf[k&1] + W2 region)
//   7. stage W2hm(k+1) (L2-hot; ~400cy latency hides under next-iter issue)
// X (the large, L3/HBM-cold half) is never vmcnt(0)-drained in the loop.
// Numerics: identical product set + accumulation order as R2 (bit-exact).
__global__ __launch_bounds__(256, 2)
void fub_db(const float* __restrict__ x, const float* __restrict__ bias,
            const unsigned char* __restrict__ ws, float* __restrict__ out)
{
    __shared__ unsigned char SB[81920];

    const int tid  = threadIdx.x;
    const int b    = blockIdx.z;
    const int o0   = blockIdx.y * 32;
    const int s0   = blockIdx.x * 32;
    const int lane = tid & 63;
    const int w    = tid >> 6;            // wave 0..3 -> tile quarter
    const int oh   = w >> 1, sh = w & 1;
    const int qd   = lane >> 4;
    const int m_   = lane & 15;
    const int ar   = 16 * oh + m_;        // o row for A/W2 frags
    const int xr   = 16 * sh + m_;        // s row for X frags

    // ---- X DMA slots: 30 over 4 waves (8,8,7,7) ----
    const int sbase = (w < 2) ? w * 8 : 16 + (w - 2) * 7;
    const int nsl   = (w < 2) ? 8 : 7;
    unsigned gX[8];
    #pragma unroll
    for (int t = 0; t < 8; t++) {
        if (t < nsl) {
            const int slot = sbase + t;
            const int p  = slot >> 1;              // plane 0..14 = j*3+sp
            const int jj = p / 3, sp = p - 3 * jj;
            const int u  = (slot & 1) * 64 + lane; // unit within plane
            const int sr = u >> 2;
            const int oc = (u & 3) ^ (sr & 3) ^ ((sr >> 2) & 3);
            gX[t] = (unsigned)(((jj * BB + b) * 3 + sp) * XW_PLANE)
                  + (unsigned)((s0 + sr) * 512 + oc * 16);
        } else gX[t] = 0;
    }
    // ---- W2 h/m DMA slots: 20 over 4 waves (5 each); plane p=slot>>1 -> (i=p>>1, sp=p&1)
    unsigned gW[5];
    #pragma unroll
    for (int t = 0; t < 5; t++) {
        const int slot = w * 5 + t;
        const int p  = slot >> 1;              // 0..9
        const int i_ = p >> 1, sp = p & 1;
        const int u  = (slot & 1) * 64 + lane;
        const int sr = u >> 2;
        const int oc = (u & 3) ^ (sr & 3) ^ ((sr >> 2) & 3);
        gW[t] = (unsigned)W2_OFF
              + (unsigned)(((i_ * 3 + sp) * CC + o0 + sr) * 512 + oc * 16);
    }

    // ---- per-lane bases ----
    const unsigned vAW = (unsigned)AW_OFF + (unsigned)(o0 + ar) * 512u + (unsigned)qd * 16u;
    const unsigned vW2 = (unsigned)W2_OFF + (unsigned)(o0 + ar) * 512u + (unsigned)qd * 16u;
    const unsigned xb  = (unsigned)(xr * 4 + (qd ^ (xr & 3) ^ ((xr >> 2) & 3))) * 16u;
    const unsigned wb  = (unsigned)(ar * 4 + (qd ^ (ar & 3) ^ ((ar >> 2) & 3))) * 16u;

    f32x4 accY[NN][NN];
    f32x4 accU[NN];
    #pragma unroll
    for (int ii = 0; ii < NN; ii++) {
        accU[ii] = (f32x4){0.f, 0.f, 0.f, 0.f};
        #pragma unroll
        for (int j = 0; j < NN; j++) accY[ii][j] = (f32x4){0.f, 0.f, 0.f, 0.f};
    }

    // ---- prologue: stage X(0) then W2hm(0) (issue order matters for vmcnt) ----
    #pragma unroll
    for (int t = 0; t < 8; t++)
        if (t < nsl) GLD16(ws + gX[t], SB + (sbase + t) * 1024);
    #pragma unroll
    for (int t = 0; t < 5; t++)
        GLD16(ws + gW[t], SB + 61440 + (w * 5 + t) * 1024);

    #pragma unroll 1
    for (int k = 0; k < 8; k++) {
        const unsigned cb = (unsigned)(k & 1) * 30720u;   // compute xbuf

        // 1. weight frags for chunk k (pre-stage so the counted wait retires them)
        short8 af[NN][3], wfl[NN];
        #pragma unroll
        for (int ii = 0; ii < NN; ii++) {
            #pragma unroll
            for (int sp = 0; sp < 3; sp++)
                af[ii][sp] = *(const short8*)(ws + vAW
                    + (unsigned)((ii * 3 + sp) * AW_PLANE) + (unsigned)(k * 64));
            wfl[ii] = *(const short8*)(ws + vW2
                    + (unsigned)((ii * 3 + 2) * AW_PLANE) + (unsigned)(k * 64));
        }
        __builtin_amdgcn_sched_barrier(0);

        // 2./3. stage X(k+1) and counted wait (X(k+1) stays in flight)
        if (k < 7) {
            const unsigned nb = 30720u - cb;
            #pragma unroll
            for (int t = 0; t < 8; t++)
                if (t < nsl) { gX[t] += 64; GLD16(ws + gX[t], SB + nb + (sbase + t) * 1024); }
            __builtin_amdgcn_sched_barrier(0);
            if (w < 2) WAITV(8); else WAITV(7);
        } else {
            WAITV(0);
        }

        // 4. chunk-k data (X, W2hm) visible to all waves
        __builtin_amdgcn_s_barrier();
        __builtin_amdgcn_sched_barrier(0);

        // 5. compute
        __builtin_amdgcn_s_setprio(1);
        #pragma unroll
        for (int j = 0; j < NN; j++) {
            const unsigned char* xp = SB + cb + (unsigned)(j * 3) * 2048u + xb;
            const short8 x0 = *(const short8*)(xp);
            const short8 x1 = *(const short8*)(xp + 2048);
            const short8 x2 = *(const short8*)(xp + 4096);
            #pragma unroll
            for (int ii = 0; ii < NN; ii++) {
                f32x4 c = accY[ii][j];
                c = MF(af[ii][0], x0, c);
                c = MF(af[ii][0], x1, c);
                c = MF(af[ii][1], x0, c);
                c = MF(af[ii][1], x1, c);
                c = MF(af[ii][0], x2, c);
                c = MF(af[ii][2], x0, c);
                accY[ii][j] = c;
            }
            {
                const unsigned char* wp = SB + 61440u + (unsigned)(j * 2) * 2048u + wb;
                const short8 wh = *(const short8*)(wp);
                const short8 wm = *(const short8*)(wp + 2048);
                f32x4 u = accU[j];
                u = MF(wh, x0, u);
                u = MF(wh, x1, u);
                u = MF(wm, x0, u);
                u = MF(wm, x1, u);
                u = MF(wh, x2, u);
                u = MF(wfl[j], x0, u);
                accU[j] = u;
            }
        }
        __builtin_amdgcn_s_setprio(0);

        // 6. all LDS reads of chunk k done -> xbuf[k&1] and W2 region reusable
        asm volatile("s_waitcnt lgkmcnt(0)" ::: "memory");
        __builtin_amdgcn_sched_barrier(0);
        __builtin_amdgcn_s_barrier();
        __builtin_amdgcn_sched_barrier(0);

        // 7. stage W2hm(k+1); its latency hides under next-iter reg-load/stage issue
        if (k < 7) {
            #pragma unroll
            for (int t = 0; t < 5; t++) {
                gW[t] += 64;
                GLD16(ws + gW[t], SB + 61440 + (w * 5 + t) * 1024);
            }
            __builtin_amdgcn_sched_barrier(0);
        }
    }

    // ---------------- epilogue (C/D: col=lane&15, row=qd*4+reg) ----------------
    const int sg  = s0 + 16 * sh + m_;
    const int og0 = o0 + 16 * oh + 4 * qd;

    float xe[NN][4];
    #pragma unroll
    for (int j = 0; j < NN; j++) {
        const float* px = x + (size_t)((j * BB + b) * CC + og0) * SSP + sg;
        #pragma unroll
        for (int r = 0; r < 4; r++) xe[j][r] = px[r * SSP];
    }

    #pragma unroll
    for (int ii = 0; ii < NN; ii++) {
        #pragma unroll
        for (int r = 0; r < 4; r++) {
            const float uu = accU[ii][r] + bias[ii * CC + og0 + r];
            float e[NN]; float mx = 0.f;
            #pragma unroll
            for (int j = 0; j < NN; j++) {
                float d = fabsf(xe[j][r] - (accY[ii][j][r] + uu));
                d = (d > THRESHV) ? d : 0.f;
                e[j] = d; mx = fmaxf(mx, d);
            }
            float sum = 0.f, hv = 0.f;
            #pragma unroll
            for (int j = 0; j < NN; j++) {
                const float p = __expf(e[j] - mx);
                sum += p; hv += p * xe[j][r];
            }
            out[(size_t)((ii * BB + b) * CC + og0 + r) * SSP + sg] = hv / sum;
        }
    }
}

// ================= fallback (R2 kernel, self-splitting; known-good) ==========
static __device__ __forceinline__ void st4(unsigned short* p, unsigned short a,
                                           unsigned short b, unsigned short c, unsigned short d) {
    ushort4 v; v.x = a; v.y = b; v.z = c; v.w = d;
    *(ushort4*)p = v;
}
#define XB 15360
__global__ __launch_bounds__(512, 2)
void fub_mfma(const float* __restrict__ x, const float* __restrict__ w,
              const float* __restrict__ bias, float* __restrict__ out)
{
    __shared__ unsigned short S[30720];
    const int tid = threadIdx.x;
    const int b = blockIdx.z, o0 = blockIdx.y * 32, s0 = blockIdx.x * 32;
    const int lane = tid & 63, wv = tid >> 6;
    const int q = wv & 3, oh = q >> 1, sh = q & 1, iset = wv >> 2, qd = lane >> 4;
    const int sub = tid >> 8, t = tid & 255;
    const int wo = t >> 3, wkg = t & 7, xs = t & 31, xkq = t >> 5;
    const int wbase = wo * 32 + (((wkg >> 1) ^ ((wo >> 1) & 3)) << 3) + ((wkg & 1) << 2);
    const int xbase = xs * 32 + (((xkq >> 1) ^ ((xs >> 1) & 3)) << 3) + ((xkq & 1) << 2);
    const int ar = 16 * oh + (lane & 15), xr = 16 * sh + (lane & 15);
    const int asw8 = ((qd ^ ((ar >> 1) & 3)) << 3), xsw8 = ((qd ^ ((xr >> 1) & 3)) << 3);
    const int arow32 = ar * 32, xrow32 = xr * 32;
    f32x4 accY[3][5]; f32x4 accU[3];
    #pragma unroll
    for (int ii = 0; ii < 3; ii++) {
        accU[ii] = (f32x4){0.f, 0.f, 0.f, 0.f};
        #pragma unroll
        for (int j = 0; j < NN; j++) accY[ii][j] = (f32x4){0.f, 0.f, 0.f, 0.f};
    }
    float w2sav[3][4];
    #pragma unroll 1
    for (int k0 = 0; k0 < CC; k0 += 32) {
        if (k0) __syncthreads();
        #pragma unroll
        for (int rep = 0; rep < 3; rep++) {
            const int i = rep * 2 + sub;
            if (i < NN) {
                const float* gw = w + (size_t)(i * CC + o0 + wo) * (2 * CC) + k0 + wkg * 4;
                const float4 w1 = *(const float4*)gw;
                const float4 w2 = *(const float4*)(gw + CC);
                w2sav[rep][0] = w2.x; w2sav[rep][1] = w2.y; w2sav[rep][2] = w2.z; w2sav[rep][3] = w2.w;
                float av[4] = {w1.x + w2.x, w1.y + w2.y, w1.z + w2.z, w1.w + w2.w};
                unsigned short h[4], m[4], l[4];
                #pragma unroll
                for (int r = 0; r < 4; r++) split3(av[r], h[r], m[r], l[r]);
                unsigned short* p = &S[i * 3 * 1024 + wbase];
                st4(p, h[0], h[1], h[2], h[3]); st4(p + 1024, m[0], m[1], m[2], m[3]); st4(p + 2048, l[0], l[1], l[2], l[3]);
            }
        }
        #pragma unroll
        for (int rep = 0; rep < 3; rep++) {
            const int j = rep * 2 + sub;
            if (j < NN) {
                const float* gx = x + (size_t)((j * BB + b) * CC + k0 + xkq * 4) * SSP + s0 + xs;
                float v[4] = {gx[0], gx[SSP], gx[2 * SSP], gx[3 * SSP]};
                unsigned short h[4], m[4], l[4];
                #pragma unroll
                for (int r = 0; r < 4; r++) split3(v[r], h[r], m[r], l[r]);
                unsigned short* p = &S[XB + j * 3 * 1024 + xbase];
                st4(p, h[0], h[1], h[2], h[3]); st4(p + 1024, m[0], m[1], m[2], m[3]); st4(p + 2048, l[0], l[1], l[2], l[3]);
            }
        }
        __syncthreads();
        short8 xf[NN][3];
        #pragma unroll
        for (int j = 0; j < NN; j++)
            #pragma unroll
            for (int sp = 0; sp < 3; sp++)
                xf[j][sp] = *(const short8*)&S[XB + (j * 3 + sp) * 1024 + xrow32 + xsw8];
#define YPL(IB_, NI_)                                                           \
        {                                                                       \
            _Pragma("unroll")                                                   \
            for (int ii = 0; ii < NI_; ii++) {                                  \
                const int i = IB_ + ii;                                         \
                const unsigned short* ap = &S[i * 3 * 1024 + arow32 + asw8];    \
                const short8 ah = *(const short8*)(ap);                         \
                const short8 am = *(const short8*)(ap + 1024);                  \
                const short8 al = *(const short8*)(ap + 2048);                  \
                _Pragma("unroll")                                               \
                for (int j = 0; j < NN; j++) {                                  \
                    f32x4 c = accY[ii][j];                                      \
                    c = MF(ah, xf[j][0], c); c = MF(ah, xf[j][1], c);           \
                    c = MF(am, xf[j][0], c); c = MF(am, xf[j][1], c);           \
                    c = MF(ah, xf[j][2], c); c = MF(al, xf[j][0], c);           \
                    accY[ii][j] = c;                                            \
                }                                                               \
            }                                                                   \
        }
        if (iset == 0) { YPL(0, 2) } else { YPL(2, 3) }
        __syncthreads();
        #pragma unroll
        for (int rep = 0; rep < 3; rep++) {
            const int i = rep * 2 + sub;
            if (i < NN) {
                unsigned short h[4], m[4], l[4];
                #pragma unroll
                for (int r = 0; r < 4; r++) split3(w2sav[rep][r], h[r], m[r], l[r]);
                unsigned short* p = &S[i * 3 * 1024 + wbase];
                st4(p, h[0], h[1], h[2], h[3]); st4(p + 1024, m[0], m[1], m[2], m[3]); st4(p + 2048, l[0], l[1], l[2], l[3]);
            }
        }
        __syncthreads();
#define UPL(IB_, NI_)                                                           \
        {                                                                       \
            _Pragma("unroll")                                                   \
            for (int ii = 0; ii < NI_; ii++) {                                  \
                const int i = IB_ + ii;                                         \
                const unsigned short* wp = &S[i * 3 * 1024 + arow32 + asw8];    \
                const short8 wh = *(const short8*)(wp);                         \
                const short8 wm = *(const short8*)(wp + 1024);                  \
                const short8 wl = *(const short8*)(wp + 2048);                  \
                f32x4 u = accU[ii];                                             \
                u = MF(wh, xf[i][0], u); u = MF(wh, xf[i][1], u);               \
                u = MF(wm, xf[i][0], u); u = MF(wm, xf[i][1], u);               \
                u = MF(wh, xf[i][2], u); u = MF(wl, xf[i][0], u);               \
                accU[ii] = u;                                                   \
            }                                                                   \
        }
        if (iset == 0) { UPL(0, 2) } else { UPL(2, 3) }
    }
    const int sg = s0 + 16 * sh + (lane & 15);
    const int og0 = o0 + 16 * oh + 4 * qd;
    float xe[NN][4];
    #pragma unroll
    for (int j = 0; j < NN; j++) {
        const float* px = x + (size_t)((j * BB + b) * CC + og0) * SSP + sg;
        #pragma unroll
        for (int r = 0; r < 4; r++) xe[j][r] = px[r * SSP];
    }
#define EPI(IB_, NI_)                                                           \
    {                                                                           \
        _Pragma("unroll")                                                       \
        for (int ii = 0; ii < NI_; ii++) {                                      \
            const int i = IB_ + ii;                                             \
            _Pragma("unroll")                                                   \
            for (int r = 0; r < 4; r++) {                                       \
                const float uu = accU[ii][r] + bias[i * CC + og0 + r];          \
                float e[NN]; float mx = 0.f;                                    \
                _Pragma("unroll")                                               \
                for (int j = 0; j < NN; j++) {                                  \
                    float d = fabsf(xe[j][r] - (accY[ii][j][r] + uu));          \
                    d = (d > THRESHV) ? d : 0.f;                                \
                    e[j] = d; mx = fmaxf(mx, d);                                \
                }                                                               \
                float sum = 0.f, hv = 0.f;                                      \
                _Pragma("unroll")                                               \
                for (int j = 0; j < NN; j++) {                                  \
                    const float p = __expf(e[j] - mx);                          \
                    sum += p; hv += p * xe[j][r];                               \
                }                                                               \
                out[(size_t)((i * BB + b) * CC + og0 + r) * SSP + sg] = hv / sum; \
            }                                                                   \
        }                                                                       \
    }
    if (iset == 0) { EPI(0, 2) } else { EPI(2, 3) }
}

extern "C" void kernel_launch(void* const* d_in, const int* in_sizes, int n_in,
                              void* d_out, int out_size, void* d_ws, size_t ws_size,
                              hipStream_t stream) {
    const float* x      = (const float*)d_in[0];
    const float* conv_w = (const float*)d_in[1];
    const float* conv_b = (const float*)d_in[2];
    float* out = (float*)d_out;

    if (ws_size >= WS_NEED) {
        unsigned char* ws = (unsigned char*)d_ws;
        prep_w<<<160, 256, 0, stream>>>(conv_w, ws);
        prep_x<<<1280, 256, 0, stream>>>(x, ws);
        dim3 grid(SSP / 32, CC / 32, BB);   // 2048 blocks, 4 waves each
        fub_db<<<grid, 256, 0, stream>>>(x, conv_b, ws, out);
    } else {
        fub_mfma<<<dim3(SSP / 32, CC / 32, BB), 512, 0, stream>>>(x, conv_w, conv_b, out);
    }
}